// Round 1
// baseline (212.801 us; speedup 1.0000x reference)
//
#include <hip/hip_runtime.h>

// Haar DWT2: x (8,64,512,512) fp32 -> (ll,lh,hl,hh) each (8,64,256,256),
// concatenated flat in d_out.
// Pure memory-bound shuffle: each thread handles one (plane, out_row, col-pair)
// work item: reads 2x float4 (rows 2i, 2i+1), writes float2 to each output.

__global__ __launch_bounds__(256) void dwt2_haar_kernel(
    const float* __restrict__ x, float* __restrict__ out, int total)
{
    // geometry constants (all powers of two):
    //   planes = 8*64 = 512, in plane = 512*512, out plane = 256*256
    //   work item: plane (9b) | out_row i (8b) | col-pair jp (7b)
    const long long OUT_SZ = 512LL * 65536LL;  // 33,554,432 elements / output

    float* __restrict__ oll = out;
    float* __restrict__ olh = out + OUT_SZ;
    float* __restrict__ ohl = out + 2 * OUT_SZ;
    float* __restrict__ ohh = out + 3 * OUT_SZ;

    for (int idx = blockIdx.x * blockDim.x + threadIdx.x; idx < total;
         idx += gridDim.x * blockDim.x) {
        int plane = idx >> 15;          // / (256*128)
        int rem   = idx & 32767;
        int i     = rem >> 7;           // out row
        int jp    = rem & 127;          // col pair (2 output cols, 4 input cols)

        long long in_off = (long long)plane * 262144 + i * 1024 + jp * 4;
        float4 r0 = *reinterpret_cast<const float4*>(x + in_off);
        float4 r1 = *reinterpret_cast<const float4*>(x + in_off + 512);

        float2 ll, lh, hl, hh;
        {
            float a00 = r0.x, a01 = r0.y, a10 = r1.x, a11 = r1.y;
            ll.x = (a00 + a01 + a10 + a11) * 0.5f;
            lh.x = (a00 + a01 - a10 - a11) * 0.5f;
            hl.x = (a00 - a01 + a10 - a11) * 0.5f;
            hh.x = (a00 - a01 - a10 + a11) * 0.5f;
        }
        {
            float a00 = r0.z, a01 = r0.w, a10 = r1.z, a11 = r1.w;
            ll.y = (a00 + a01 + a10 + a11) * 0.5f;
            lh.y = (a00 + a01 - a10 - a11) * 0.5f;
            hl.y = (a00 - a01 + a10 - a11) * 0.5f;
            hh.y = (a00 - a01 - a10 + a11) * 0.5f;
        }

        long long o = (long long)plane * 65536 + i * 256 + jp * 2;
        *reinterpret_cast<float2*>(oll + o) = ll;
        *reinterpret_cast<float2*>(olh + o) = lh;
        *reinterpret_cast<float2*>(ohl + o) = hl;
        *reinterpret_cast<float2*>(ohh + o) = hh;
    }
}

extern "C" void kernel_launch(void* const* d_in, const int* in_sizes, int n_in,
                              void* d_out, int out_size, void* d_ws, size_t ws_size,
                              hipStream_t stream) {
    const float* x = (const float*)d_in[0];
    float* out = (float*)d_out;

    const int total = 512 * 256 * 128;  // 16,777,216 work items
    const int block = 256;
    const int grid = 2048;              // 256 CU x 8 blocks/CU, grid-stride

    dwt2_haar_kernel<<<grid, block, 0, stream>>>(x, out, total);
}

// Round 2
// 203.197 us; speedup vs baseline: 1.0473x; 1.0473x over previous
//
#include <hip/hip_runtime.h>

// Haar DWT2: x (8,64,512,512) fp32 -> (ll,lh,hl,hh) each (8,64,256,256),
// concatenated flat in d_out.
// Memory-bound shuffle. Each work item = (plane, out_row, col-quad):
// reads 8 input cols from rows 2i/2i+1 (4x float4), writes one float4 to
// each of the 4 outputs (16B stores everywhere).

__global__ __launch_bounds__(256) void dwt2_haar_kernel(
    const float* __restrict__ x, float* __restrict__ out, int total)
{
    const long long OUT_SZ = 512LL * 65536LL;  // 33,554,432 elements / output

    float* __restrict__ oll = out;
    float* __restrict__ olh = out + OUT_SZ;
    float* __restrict__ ohl = out + 2 * OUT_SZ;
    float* __restrict__ ohh = out + 3 * OUT_SZ;

    for (int idx = blockIdx.x * blockDim.x + threadIdx.x; idx < total;
         idx += gridDim.x * blockDim.x) {
        // work item: plane (9b) | out_row i (8b) | col-quad jq (6b)
        int plane = idx >> 14;          // / (256*64)
        int rem   = idx & 16383;
        int i     = rem >> 6;           // out row
        int jq    = rem & 63;           // quad of output cols (8 input cols)

        long long in_off = (long long)plane * 262144 + i * 1024 + jq * 8;
        float4 r0a = *reinterpret_cast<const float4*>(x + in_off);
        float4 r0b = *reinterpret_cast<const float4*>(x + in_off + 4);
        float4 r1a = *reinterpret_cast<const float4*>(x + in_off + 512);
        float4 r1b = *reinterpret_cast<const float4*>(x + in_off + 516);

        float4 ll, lh, hl, hh;
        {
            float a00 = r0a.x, a01 = r0a.y, a10 = r1a.x, a11 = r1a.y;
            ll.x = (a00 + a01 + a10 + a11) * 0.5f;
            lh.x = (a00 + a01 - a10 - a11) * 0.5f;
            hl.x = (a00 - a01 + a10 - a11) * 0.5f;
            hh.x = (a00 - a01 - a10 + a11) * 0.5f;
        }
        {
            float a00 = r0a.z, a01 = r0a.w, a10 = r1a.z, a11 = r1a.w;
            ll.y = (a00 + a01 + a10 + a11) * 0.5f;
            lh.y = (a00 + a01 - a10 - a11) * 0.5f;
            hl.y = (a00 - a01 + a10 - a11) * 0.5f;
            hh.y = (a00 - a01 - a10 + a11) * 0.5f;
        }
        {
            float a00 = r0b.x, a01 = r0b.y, a10 = r1b.x, a11 = r1b.y;
            ll.z = (a00 + a01 + a10 + a11) * 0.5f;
            lh.z = (a00 + a01 - a10 - a11) * 0.5f;
            hl.z = (a00 - a01 + a10 - a11) * 0.5f;
            hh.z = (a00 - a01 - a10 + a11) * 0.5f;
        }
        {
            float a00 = r0b.z, a01 = r0b.w, a10 = r1b.z, a11 = r1b.w;
            ll.w = (a00 + a01 + a10 + a11) * 0.5f;
            lh.w = (a00 + a01 - a10 - a11) * 0.5f;
            hl.w = (a00 - a01 + a10 - a11) * 0.5f;
            hh.w = (a00 - a01 - a10 + a11) * 0.5f;
        }

        long long o = (long long)plane * 65536 + i * 256 + jq * 4;
        *reinterpret_cast<float4*>(oll + o) = ll;
        *reinterpret_cast<float4*>(olh + o) = lh;
        *reinterpret_cast<float4*>(ohl + o) = hl;
        *reinterpret_cast<float4*>(ohh + o) = hh;
    }
}

extern "C" void kernel_launch(void* const* d_in, const int* in_sizes, int n_in,
                              void* d_out, int out_size, void* d_ws, size_t ws_size,
                              hipStream_t stream) {
    const float* x = (const float*)d_in[0];
    float* out = (float*)d_out;

    const int total = 512 * 256 * 64;   // 8,388,608 work items
    const int block = 256;
    const int grid = 2048;              // 256 CU x 8 blocks/CU, grid-stride

    dwt2_haar_kernel<<<grid, block, 0, stream>>>(x, out, total);
}

// Round 4
// 198.810 us; speedup vs baseline: 1.0704x; 1.0221x over previous
//
#include <hip/hip_runtime.h>

// Haar DWT2: x (8,64,512,512) fp32 -> (ll,lh,hl,hh) each (8,64,256,256),
// concatenated flat in d_out.
// Memory-bound shuffle. Each work item = (plane, out_row, col-quad):
// reads 8 input cols from rows 2i/2i+1 (4x 16B), writes one 16B vector to
// each of the 4 outputs. Non-temporal loads/stores (single-use streams) +
// 2-way unroll for deeper MLP.
// Note: __builtin_nontemporal_* requires a true clang vector type, not
// HIP's struct float4 — use ext_vector_type(4).

typedef float v4f __attribute__((ext_vector_type(4)));

__device__ __forceinline__ void dwt_item(const float* __restrict__ x,
                                         float* __restrict__ oll,
                                         float* __restrict__ olh,
                                         float* __restrict__ ohl,
                                         float* __restrict__ ohh,
                                         int idx)
{
    // work item: plane (9b) | out_row i (8b) | col-quad jq (6b)
    int plane = idx >> 14;
    int rem   = idx & 16383;
    int i     = rem >> 6;
    int jq    = rem & 63;

    long long in_off = (long long)plane * 262144 + i * 1024 + jq * 8;
    v4f r0a = __builtin_nontemporal_load(reinterpret_cast<const v4f*>(x + in_off));
    v4f r0b = __builtin_nontemporal_load(reinterpret_cast<const v4f*>(x + in_off + 4));
    v4f r1a = __builtin_nontemporal_load(reinterpret_cast<const v4f*>(x + in_off + 512));
    v4f r1b = __builtin_nontemporal_load(reinterpret_cast<const v4f*>(x + in_off + 516));

    v4f ll, lh, hl, hh;
    {
        float s0 = r0a.x + r0a.y, d0 = r0a.x - r0a.y;
        float s1 = r1a.x + r1a.y, d1 = r1a.x - r1a.y;
        ll.x = (s0 + s1) * 0.5f; lh.x = (s0 - s1) * 0.5f;
        hl.x = (d0 + d1) * 0.5f; hh.x = (d0 - d1) * 0.5f;
    }
    {
        float s0 = r0a.z + r0a.w, d0 = r0a.z - r0a.w;
        float s1 = r1a.z + r1a.w, d1 = r1a.z - r1a.w;
        ll.y = (s0 + s1) * 0.5f; lh.y = (s0 - s1) * 0.5f;
        hl.y = (d0 + d1) * 0.5f; hh.y = (d0 - d1) * 0.5f;
    }
    {
        float s0 = r0b.x + r0b.y, d0 = r0b.x - r0b.y;
        float s1 = r1b.x + r1b.y, d1 = r1b.x - r1b.y;
        ll.z = (s0 + s1) * 0.5f; lh.z = (s0 - s1) * 0.5f;
        hl.z = (d0 + d1) * 0.5f; hh.z = (d0 - d1) * 0.5f;
    }
    {
        float s0 = r0b.z + r0b.w, d0 = r0b.z - r0b.w;
        float s1 = r1b.z + r1b.w, d1 = r1b.z - r1b.w;
        ll.w = (s0 + s1) * 0.5f; lh.w = (s0 - s1) * 0.5f;
        hl.w = (d0 + d1) * 0.5f; hh.w = (d0 - d1) * 0.5f;
    }

    long long o = (long long)plane * 65536 + i * 256 + jq * 4;
    __builtin_nontemporal_store(ll, reinterpret_cast<v4f*>(oll + o));
    __builtin_nontemporal_store(lh, reinterpret_cast<v4f*>(olh + o));
    __builtin_nontemporal_store(hl, reinterpret_cast<v4f*>(ohl + o));
    __builtin_nontemporal_store(hh, reinterpret_cast<v4f*>(ohh + o));
}

__global__ __launch_bounds__(256) void dwt2_haar_kernel(
    const float* __restrict__ x, float* __restrict__ out, int total)
{
    const long long OUT_SZ = 512LL * 65536LL;

    float* __restrict__ oll = out;
    float* __restrict__ olh = out + OUT_SZ;
    float* __restrict__ ohl = out + 2 * OUT_SZ;
    float* __restrict__ ohh = out + 3 * OUT_SZ;

    const int stride = gridDim.x * blockDim.x;
    int idx = blockIdx.x * blockDim.x + threadIdx.x;

    // 2-way unroll: total = 8,388,608, stride = 524,288 -> 16 items/thread,
    // 8 unrolled trips. No remainder for this fixed shape.
    for (; idx + stride < total; idx += 2 * stride) {
        dwt_item(x, oll, olh, ohl, ohh, idx);
        dwt_item(x, oll, olh, ohl, ohh, idx + stride);
    }
    for (; idx < total; idx += stride) {
        dwt_item(x, oll, olh, ohl, ohh, idx);
    }
}

extern "C" void kernel_launch(void* const* d_in, const int* in_sizes, int n_in,
                              void* d_out, int out_size, void* d_ws, size_t ws_size,
                              hipStream_t stream) {
    const float* x = (const float*)d_in[0];
    float* out = (float*)d_out;

    const int total = 512 * 256 * 64;   // 8,388,608 work items
    const int block = 256;
    const int grid = 2048;

    dwt2_haar_kernel<<<grid, block, 0, stream>>>(x, out, total);
}